// Round 2
// baseline (145.224 us; speedup 1.0000x reference)
//
#include <hip/hip_runtime.h>

// ECT: x[N,3] f32, v[3,64] f32, batch[N] int32 (sorted, 64 batches)
// out[64,64,64] f32 = cumsum over bins of per-(batch,bin,dir) histogram.
#define RES 64
#define T_DIRS 64
#define NUM_B 64
#define CHUNK 2048
#define MAXC 32   // covers batch sizes up to 65536 (actual ~16.4K)

__device__ __forceinline__ int lower_bound_i32(const int* __restrict__ a,
                                               int n, int val) {
    int lo = 0, hi = n;
    while (lo < hi) {
        int mid = (lo + hi) >> 1;
        if (a[mid] < val) lo = mid + 1; else hi = mid;
    }
    return lo;
}

__global__ __launch_bounds__(256) void ect_zero_kernel(unsigned* __restrict__ u) {
    u[blockIdx.x * 256 + threadIdx.x] = 0u;   // grid = 262144/256 = 1024 blocks
}

__global__ __launch_bounds__(256) void ect_hist_kernel(
    const float* __restrict__ x, const float* __restrict__ v,
    const int* __restrict__ batch, unsigned* __restrict__ counts, int N)
{
    const int b = blockIdx.y;   // batch id
    const int c = blockIdx.x;   // chunk within batch

    // batch is sorted: find this batch's point range (uniform across block).
    int start = lower_bound_i32(batch, N, b);
    int end   = lower_bound_i32(batch, N, b + 1);
    start += c * CHUNK;
    if (start >= end) return;          // uniform early-exit (before any barrier)
    const int stop = min(start + CHUNK, end);

    __shared__ unsigned hist[RES * T_DIRS];   // 16 KB
    for (int i = threadIdx.x; i < RES * T_DIRS; i += 256) hist[i] = 0u;
    __syncthreads();

    // lane owns direction t; all 64 lanes of a wave share one point p.
    const int t = threadIdx.x & 63;
    const float v0 = v[t];
    const float v1 = v[T_DIRS + t];
    const float v2 = v[2 * T_DIRS + t];
    const float S = 64.0f / 2.2f;      // RES / (2*RADIUS)
    // bin = floor((nh+1.1)/2.2*64) = floor(nh*S + 32), clipped to [0,63]

    #pragma unroll 4
    for (int p = start + (threadIdx.x >> 6); p < stop; p += 4) {
        const float* xp = x + 3 * p;          // wave-uniform address
        float x0 = xp[0], x1 = xp[1], x2 = xp[2];
        float nh = fmaf(x0, v0, fmaf(x1, v1, x2 * v2));
        float f = fmaf(nh, S, 32.0f);
        f = fminf(fmaxf(f, 0.0f), 63.0f);
        int bin = (int)f;                      // trunc == floor after clamp
        atomicAdd(&hist[(bin << 6) + t], 1u);  // LDS atomic, distinct addr/lane
    }
    __syncthreads();

    // flush block-private histogram to global (exact uint atomics)
    unsigned* __restrict__ gb = counts + b * (RES * T_DIRS);
    for (int i = threadIdx.x; i < RES * T_DIRS; i += 256) {
        unsigned h = hist[i];
        if (h) atomicAdd(&gb[i], h);
    }
}

// In-place: d_out holds uint counts [64][64][64]; convert to cumulative f32
// over the bin axis. One thread per (b,t) column; read-all then write-all.
__global__ __launch_bounds__(256) void ect_cumsum_kernel(unsigned* __restrict__ u)
{
    int gid = blockIdx.x * 256 + threadIdx.x;   // 0..4095
    int b = gid >> 6, t = gid & 63;
    int base = b * (RES * T_DIRS) + t;

    unsigned vals[RES];
    #pragma unroll
    for (int r = 0; r < RES; ++r) vals[r] = u[base + (r << 6)];

    unsigned acc = 0u;
    #pragma unroll
    for (int r = 0; r < RES; ++r) {
        acc += vals[r];
        u[base + (r << 6)] = __float_as_uint((float)acc);  // counts < 2^24: exact
    }
}

extern "C" void kernel_launch(void* const* d_in, const int* in_sizes, int n_in,
                              void* d_out, int out_size, void* d_ws, size_t ws_size,
                              hipStream_t stream) {
    const float* x = (const float*)d_in[0];          // [N,3]
    const float* v = (const float*)d_in[1];          // [3,64]
    const int* batch = (const int*)d_in[2];          // [N] int32, sorted
    const int N = in_sizes[2];

    // zero the count accumulator (d_out reinterpreted as uint); capture-safe
    ect_zero_kernel<<<(NUM_B * RES * T_DIRS) / 256, 256, 0, stream>>>((unsigned*)d_out);

    dim3 grid(MAXC, NUM_B);
    ect_hist_kernel<<<grid, 256, 0, stream>>>(x, v, batch, (unsigned*)d_out, N);

    ect_cumsum_kernel<<<(NUM_B * T_DIRS) / 256, 256, 0, stream>>>((unsigned*)d_out);
}

// Round 3
// 50.581 us; speedup vs baseline: 2.8711x; 2.8711x over previous
//
#include <hip/hip_runtime.h>

// ECT: x[N,3] f32, v[3,64] f32, batch[N] int32 (sorted, 64 batches)
// out[64,64,64] f32 = cumsum over bins of per-(batch,bin,dir) histogram.
#define RES 64
#define TD 64
#define NB 64
#define BLK 1024            // 16 waves per block
#define WAVES (BLK / 64)
#define CHUNK 2048          // points per block
#define MAXC 10             // covers batch sizes up to 20480 (actual ~16.4K)

// Zero the count accumulator AND precompute batch boundaries (block 0 only):
// 65 lanes each binary-search one lower bound in parallel.
__global__ __launch_bounds__(256) void ect_init_kernel(
    const int* __restrict__ batch, int N,
    unsigned* __restrict__ counts, int* __restrict__ offs)
{
    int gid = blockIdx.x * 256 + threadIdx.x;     // grid: 1024 blocks
    counts[gid] = 0u;                             // 262144 entries exactly
    if (blockIdx.x == 0 && threadIdx.x <= NB) {
        int val = (int)threadIdx.x;
        int lo = 0, hi = N;
        while (lo < hi) {
            int mid = (lo + hi) >> 1;
            if (batch[mid] < val) lo = mid + 1; else hi = mid;
        }
        offs[threadIdx.x] = lo;
    }
}

__global__ __launch_bounds__(BLK) void ect_hist_kernel(
    const float* __restrict__ x, const float* __restrict__ v,
    const int* __restrict__ offs, unsigned* __restrict__ counts)
{
    const int b = blockIdx.y;   // batch id
    const int c = blockIdx.x;   // chunk within batch

    const int bend = offs[b + 1];
    int start = offs[b] + c * CHUNK;
    if (start >= bend) return;          // uniform early-exit (before barriers)
    const int stop = min(start + CHUNK, bend);

    __shared__ unsigned hist[RES * TD];   // 16 KB
    for (int i = threadIdx.x; i < RES * TD; i += BLK) hist[i] = 0u;
    __syncthreads();

    // lane owns direction t; all 64 lanes of a wave share each point.
    const int t = threadIdx.x & 63;
    const int w = threadIdx.x >> 6;     // wave id 0..15
    const float v0 = v[t];
    const float v1 = v[TD + t];
    const float v2 = v[2 * TD + t];
    const float S = 64.0f / 2.2f;       // RES / (2*RADIUS)
    // bin = floor(nh*S + 32), clipped to [0,63]

#define PROC(x0, x1, x2) {                                   \
        float nh = fmaf((x0), v0, fmaf((x1), v1, (x2) * v2));\
        float f = fmaf(nh, S, 32.0f);                        \
        f = fminf(fmaxf(f, 0.0f), 63.0f);                    \
        int bin = (int)f;                                    \
        atomicAdd(&hist[(bin << 6) + t], 1u); }

    // 4-point groups from a 4-aligned base so float4 loads are 16B-aligned.
    const int abase = start & ~3;
    const int ngroups = (stop - abase + 3) >> 2;
    for (int g = w; g < ngroups; g += WAVES) {
        const int p0 = abase + (g << 2);
        if (p0 >= start && p0 + 4 <= stop) {     // full interior group (common)
            const float4* xp = (const float4*)(x + 3 * p0);  // wave-uniform
            float4 A = xp[0], B = xp[1], C = xp[2];
            PROC(A.x, A.y, A.z);
            PROC(A.w, B.x, B.y);
            PROC(B.z, B.w, C.x);
            PROC(C.y, C.z, C.w);
        } else {                                 // ragged head/tail group
            for (int i = 0; i < 4; ++i) {
                int p = p0 + i;
                if (p >= start && p < stop) {
                    float x0 = x[3 * p], x1 = x[3 * p + 1], x2 = x[3 * p + 2];
                    PROC(x0, x1, x2);
                }
            }
        }
    }
#undef PROC
    __syncthreads();

    // flush block-private histogram to global (exact uint atomics)
    unsigned* __restrict__ gb = counts + b * (RES * TD);
    for (int i = threadIdx.x; i < RES * TD; i += BLK) {
        unsigned h = hist[i];
        if (h) atomicAdd(&gb[i], h);
    }
}

// In-place: d_out holds uint counts [64][64][64]; convert to cumulative f32
// over the bin axis. One thread per (b,t) column.
__global__ __launch_bounds__(256) void ect_cumsum_kernel(unsigned* __restrict__ u)
{
    int gid = blockIdx.x * 256 + threadIdx.x;   // 0..4095
    int b = gid >> 6, t = gid & 63;
    int base = b * (RES * TD) + t;

    unsigned vals[RES];
    #pragma unroll
    for (int r = 0; r < RES; ++r) vals[r] = u[base + (r << 6)];

    unsigned acc = 0u;
    #pragma unroll
    for (int r = 0; r < RES; ++r) {
        acc += vals[r];
        u[base + (r << 6)] = __float_as_uint((float)acc);  // counts < 2^24: exact
    }
}

extern "C" void kernel_launch(void* const* d_in, const int* in_sizes, int n_in,
                              void* d_out, int out_size, void* d_ws, size_t ws_size,
                              hipStream_t stream) {
    const float* x = (const float*)d_in[0];          // [N,3]
    const float* v = (const float*)d_in[1];          // [3,64]
    const int* batch = (const int*)d_in[2];          // [N] int32, sorted
    const int N = in_sizes[2];
    int* offs = (int*)d_ws;                          // 65 ints of scratch

    ect_init_kernel<<<(NB * RES * TD) / 256, 256, 0, stream>>>(
        batch, N, (unsigned*)d_out, offs);

    dim3 grid(MAXC, NB);
    ect_hist_kernel<<<grid, BLK, 0, stream>>>(x, v, offs, (unsigned*)d_out);

    ect_cumsum_kernel<<<(NB * TD) / 256, 256, 0, stream>>>((unsigned*)d_out);
}

// Round 4
// 38.527 us; speedup vs baseline: 3.7695x; 1.3129x over previous
//
#include <hip/hip_runtime.h>

// ECT: x[N,3] f32, v[3,64] f32, batch[N] int32 (sorted, 64 batches)
// out[64,64,64] f32 = cumsum over bins of per-(batch,bin,dir) histogram.
#define RES 64
#define TD 64
#define NB 64
#define BLK 1024            // 16 waves per block
#define WAVES (BLK / 64)
#define CHUNK 2048          // points per block
#define MAXC 10             // covers batch sizes up to 20480 (actual ~16.4K)

// Zero the count accumulator AND precompute batch boundaries (block 0 only).
__global__ __launch_bounds__(256) void ect_init_kernel(
    const int* __restrict__ batch, int N,
    unsigned* __restrict__ counts, int* __restrict__ offs)
{
    int gid = blockIdx.x * 256 + threadIdx.x;     // grid: 1024 blocks
    counts[gid] = 0u;                             // 262144 entries exactly
    if (blockIdx.x == 0 && threadIdx.x <= NB) {
        int val = (int)threadIdx.x;
        int lo = 0, hi = N;
        while (lo < hi) {
            int mid = (lo + hi) >> 1;
            if (batch[mid] < val) lo = mid + 1; else hi = mid;
        }
        offs[threadIdx.x] = lo;
    }
}

__global__ __launch_bounds__(BLK) void ect_hist_kernel(
    const float* __restrict__ x, const float* __restrict__ v,
    const int* __restrict__ offs, unsigned* __restrict__ counts)
{
    const int b = blockIdx.y;   // batch id
    const int c = blockIdx.x;   // chunk within batch

    const int bend = offs[b + 1];
    const int start = offs[b] + c * CHUNK;
    if (start >= bend) return;          // uniform early-exit (before barriers)
    const int stop = min(start + CHUNK, bend);

    __shared__ unsigned hist[RES * TD];   // 16 KB
    for (int i = threadIdx.x; i < RES * TD; i += BLK) hist[i] = 0u;
    __syncthreads();

    // lane owns direction t; wave broadcasts each point from registers.
    const int t = threadIdx.x & 63;     // == lane id
    const int w = threadIdx.x >> 6;     // wave id 0..15
    const float S = 64.0f / 2.2f;       // RES / (2*RADIUS)
    const float v0S = v[t] * S;
    const float v1S = v[TD + t] * S;
    const float v2S = v[2 * TD + t] * S;
    // bin = floor(x·v * S + 32), clipped to [0,63]

    // 64-point tiles: 3 coalesced per-lane loads cover 192 floats; point j's
    // coord k sits at flat offset q=3j+k -> register q>>6, lane q&63 (all
    // compile-time constants after full unroll -> v_readlane, no LDS).
#define SELREG(q) ((q) < 64 ? l0 : ((q) < 128 ? l1 : l2))
#define RD(q) __uint_as_float(__builtin_amdgcn_readlane(__float_as_uint(SELREG(q)), (q) & 63))
#define PROC(j) {                                                      \
        float x0 = RD(3*(j)), x1 = RD(3*(j)+1), x2 = RD(3*(j)+2);      \
        float f = fmaf(x0, v0S, fmaf(x1, v1S, fmaf(x2, v2S, 32.0f)));  \
        f = __builtin_amdgcn_fmed3f(f, 0.0f, 63.0f);                   \
        int bin = (int)f;                                              \
        atomicAdd(&hist[(bin << 6) + t], 1u); }

    const int ntiles = (stop - start + 63) >> 6;
    for (int tile = w; tile < ntiles; tile += WAVES) {
        const int p0 = start + (tile << 6);
        const int cnt = min(64, stop - p0);
        const int fb = 3 * p0 + t;
        float l0, l1, l2;
        if (cnt == 64) {                       // full tile (common case)
            l0 = x[fb]; l1 = x[fb + 64]; l2 = x[fb + 128];
            #pragma unroll
            for (int j = 0; j < 64; ++j) PROC(j);
        } else {                               // ragged tail tile
            const int lim = 3 * stop;
            l0 = (fb       < lim) ? x[fb]       : 0.0f;
            l1 = (fb +  64 < lim) ? x[fb +  64] : 0.0f;
            l2 = (fb + 128 < lim) ? x[fb + 128] : 0.0f;
            #pragma unroll
            for (int j = 0; j < 64; ++j) {
                if (j < cnt) PROC(j);          // wave-uniform guard
            }
        }
    }
#undef PROC
#undef RD
#undef SELREG
    __syncthreads();

    // flush block-private histogram to global (exact uint atomics)
    unsigned* __restrict__ gb = counts + b * (RES * TD);
    for (int i = threadIdx.x; i < RES * TD; i += BLK) {
        unsigned h = hist[i];
        if (h) atomicAdd(&gb[i], h);
    }
}

// In-place: d_out holds uint counts [64][64][64]; convert to cumulative f32
// over the bin axis. One thread per (b,t) column.
__global__ __launch_bounds__(256) void ect_cumsum_kernel(unsigned* __restrict__ u)
{
    int gid = blockIdx.x * 256 + threadIdx.x;   // 0..4095
    int b = gid >> 6, t = gid & 63;
    int base = b * (RES * TD) + t;

    unsigned vals[RES];
    #pragma unroll
    for (int r = 0; r < RES; ++r) vals[r] = u[base + (r << 6)];

    unsigned acc = 0u;
    #pragma unroll
    for (int r = 0; r < RES; ++r) {
        acc += vals[r];
        u[base + (r << 6)] = __float_as_uint((float)acc);  // counts < 2^24: exact
    }
}

extern "C" void kernel_launch(void* const* d_in, const int* in_sizes, int n_in,
                              void* d_out, int out_size, void* d_ws, size_t ws_size,
                              hipStream_t stream) {
    const float* x = (const float*)d_in[0];          // [N,3]
    const float* v = (const float*)d_in[1];          // [3,64]
    const int* batch = (const int*)d_in[2];          // [N] int32, sorted
    const int N = in_sizes[2];
    int* offs = (int*)d_ws;                          // 65 ints of scratch

    ect_init_kernel<<<(NB * RES * TD) / 256, 256, 0, stream>>>(
        batch, N, (unsigned*)d_out, offs);

    dim3 grid(MAXC, NB);
    ect_hist_kernel<<<grid, BLK, 0, stream>>>(x, v, offs, (unsigned*)d_out);

    ect_cumsum_kernel<<<(NB * TD) / 256, 256, 0, stream>>>((unsigned*)d_out);
}

// Round 5
// 35.902 us; speedup vs baseline: 4.0451x; 1.0731x over previous
//
#include <hip/hip_runtime.h>

// ECT: x[N,3] f32, v[3,64] f32, batch[N] int32 (sorted, 64 batches)
// out[64,64,64] f32 = cumsum over bins of per-(batch,bin,dir) histogram.
#define RES 64
#define TD 64
#define NB 64
#define BLK 1024            // 16 waves per block
#define WAVES (BLK / 64)
#define CHUNK 2048          // points per block (flat grid: N/CHUNK blocks)

// Zero the count accumulator AND precompute batch boundaries (block 0 only).
__global__ __launch_bounds__(256) void ect_init_kernel(
    const int* __restrict__ batch, int N,
    unsigned* __restrict__ counts, int* __restrict__ offs)
{
    int gid = blockIdx.x * 256 + threadIdx.x;     // grid: 1024 blocks
    counts[gid] = 0u;                             // 262144 entries exactly
    if (blockIdx.x == 0 && threadIdx.x <= NB) {
        int val = (int)threadIdx.x;
        int lo = 0, hi = N;
        while (lo < hi) {
            int mid = (lo + hi) >> 1;
            if (batch[mid] < val) lo = mid + 1; else hi = mid;
        }
        offs[threadIdx.x] = lo;                   // offs[64] == N
    }
}

__global__ __launch_bounds__(BLK) void ect_hist_kernel(
    const float* __restrict__ x, const float* __restrict__ v,
    const int* __restrict__ offs, unsigned* __restrict__ counts, int N)
{
    const int start = blockIdx.x * CHUNK;         // flat, perfectly balanced
    const int stop  = min(start + CHUNK, N);
    if (start >= N) return;

    __shared__ unsigned hist[RES * TD];           // 16 KB

    // lane owns direction t; wave broadcasts each point from registers.
    const int t = threadIdx.x & 63;               // == lane id
    const int w = threadIdx.x >> 6;               // wave id 0..15
    const float S = 64.0f / 2.2f;                 // RES / (2*RADIUS)
    const float v0S = v[t] * S;
    const float v1S = v[TD + t] * S;
    const float v2S = v[2 * TD + t] * S;
    // bin = floor(x·v * S + 32), clipped to [0,63]

    // batch of first point: largest b with offs[b] <= start (uniform)
    int lo = 0, hi = NB;
    while (lo < hi) {
        int mid = (lo + hi + 1) >> 1;
        if (offs[mid] <= start) lo = mid; else hi = mid - 1;
    }
    int b = lo;

#define SELREG(q) ((q) < 64 ? l0 : ((q) < 128 ? l1 : l2))
#define RD(q) __uint_as_float(__builtin_amdgcn_readlane(__float_as_uint(SELREG(q)), (q) & 63))
#define PROC(j) {                                                      \
        float x0 = RD(3*(j)), x1 = RD(3*(j)+1), x2 = RD(3*(j)+2);      \
        float f = fmaf(x0, v0S, fmaf(x1, v1S, fmaf(x2, v2S, 32.0f)));  \
        f = __builtin_amdgcn_fmed3f(f, 0.0f, 63.0f);                   \
        int bin = (int)f;                                              \
        atomicAdd(&hist[(bin << 6) + t], 1u); }

    int seg = start;
    while (seg < stop) {                          // one iter per batch segment
        while (offs[b + 1] <= seg) ++b;           // skip empty batches (uniform)
        const int segend = min(stop, offs[b + 1]);

        for (int i = threadIdx.x; i < RES * TD; i += BLK) hist[i] = 0u;
        __syncthreads();

        // 64-point tiles: 3 coalesced per-lane loads cover 192 floats; point
        // j's coord k at flat offset q=3j+k -> register q>>6, lane q&63 (all
        // compile-time after full unroll -> v_readlane, no LDS staging).
        const int ntiles = (segend - seg + 63) >> 6;
        for (int tile = w; tile < ntiles; tile += WAVES) {
            const int p0 = seg + (tile << 6);
            const int cnt = min(64, segend - p0);
            const int fb = 3 * p0 + t;
            float l0, l1, l2;
            if (cnt == 64) {                      // full tile (common case)
                l0 = x[fb]; l1 = x[fb + 64]; l2 = x[fb + 128];
                #pragma unroll
                for (int j = 0; j < 64; ++j) PROC(j);
            } else {                              // ragged segment-tail tile
                const int lim = 3 * segend;
                l0 = (fb       < lim) ? x[fb]       : 0.0f;
                l1 = (fb +  64 < lim) ? x[fb +  64] : 0.0f;
                l2 = (fb + 128 < lim) ? x[fb + 128] : 0.0f;
                #pragma unroll
                for (int j = 0; j < 64; ++j) {
                    if (j < cnt) PROC(j);         // wave-uniform guard
                }
            }
        }
        __syncthreads();

        // flush block-private histogram into batch b's slab (exact uint)
        unsigned* __restrict__ gb = counts + b * (RES * TD);
        for (int i = threadIdx.x; i < RES * TD; i += BLK) {
            unsigned h = hist[i];
            if (h) atomicAdd(&gb[i], h);
        }
        if (segend < stop) __syncthreads();       // before re-zeroing hist
        seg = segend;
    }
#undef PROC
#undef RD
#undef SELREG
}

// In-place: d_out holds uint counts [64][64][64]; convert to cumulative f32
// over the bin axis. One thread per (b,t) column.
__global__ __launch_bounds__(256) void ect_cumsum_kernel(unsigned* __restrict__ u)
{
    int gid = blockIdx.x * 256 + threadIdx.x;   // 0..4095
    int b = gid >> 6, t = gid & 63;
    int base = b * (RES * TD) + t;

    unsigned vals[RES];
    #pragma unroll
    for (int r = 0; r < RES; ++r) vals[r] = u[base + (r << 6)];

    unsigned acc = 0u;
    #pragma unroll
    for (int r = 0; r < RES; ++r) {
        acc += vals[r];
        u[base + (r << 6)] = __float_as_uint((float)acc);  // counts < 2^24: exact
    }
}

extern "C" void kernel_launch(void* const* d_in, const int* in_sizes, int n_in,
                              void* d_out, int out_size, void* d_ws, size_t ws_size,
                              hipStream_t stream) {
    const float* x = (const float*)d_in[0];          // [N,3]
    const float* v = (const float*)d_in[1];          // [3,64]
    const int* batch = (const int*)d_in[2];          // [N] int32, sorted
    const int N = in_sizes[2];
    int* offs = (int*)d_ws;                          // 65 ints of scratch

    ect_init_kernel<<<(NB * RES * TD) / 256, 256, 0, stream>>>(
        batch, N, (unsigned*)d_out, offs);

    const int nblocks = (N + CHUNK - 1) / CHUNK;     // 512 for N=1M
    ect_hist_kernel<<<nblocks, BLK, 0, stream>>>(x, v, offs, (unsigned*)d_out, N);

    ect_cumsum_kernel<<<(NB * TD) / 256, 256, 0, stream>>>((unsigned*)d_out);
}

// Round 6
// 33.891 us; speedup vs baseline: 4.2850x; 1.0593x over previous
//
#include <hip/hip_runtime.h>

// ECT: x[N,3] f32, v[3,64] f32, batch[N] int32 (sorted, 64 batches)
// out[64,64,64] f32 = cumsum over bins of per-(batch,bin,dir) histogram.
#define RES 64
#define TD 64
#define NB 64
#define BLK 1024            // 16 waves per block
#define WAVES 16
#define CHUNK 2048          // points per block (flat grid: N/CHUNK blocks)

// Zero the count accumulator AND precompute batch boundaries (block 0 only).
__global__ __launch_bounds__(256) void ect_init_kernel(
    const int* __restrict__ batch, int N,
    unsigned* __restrict__ counts, int* __restrict__ offs)
{
    int gid = blockIdx.x * 256 + threadIdx.x;     // grid: 1024 blocks
    counts[gid] = 0u;                             // 262144 entries exactly
    if (blockIdx.x == 0 && threadIdx.x <= NB) {
        int val = (int)threadIdx.x;
        int lo = 0, hi = N;
        while (lo < hi) {
            int mid = (lo + hi) >> 1;
            if (batch[mid] < val) lo = mid + 1; else hi = mid;
        }
        offs[threadIdx.x] = lo;                   // offs[64] == N
    }
}

__global__ __launch_bounds__(BLK) void ect_hist_kernel(
    const float* __restrict__ x, const float* __restrict__ v,
    const int* __restrict__ offs, unsigned* __restrict__ counts, int N)
{
    const int start = blockIdx.x * CHUNK;         // flat, perfectly balanced
    const int stop  = min(start + CHUNK, N);
    if (start >= N) return;

    // Two wave-group-private histograms: halves same-address atomic contention.
    __shared__ unsigned hist[2][RES * TD];        // 32 KB -> still 2 blocks/CU

    const int t = threadIdx.x & 63;               // lane id = direction
    const int w = threadIdx.x >> 6;               // wave id 0..15
    unsigned* __restrict__ hw = hist[w >> 3];     // waves 0-7 -> A, 8-15 -> B
    const float S = 64.0f / 2.2f;                 // RES / (2*RADIUS)
    const float v0S = v[t] * S;
    const float v1S = v[TD + t] * S;
    const float v2S = v[2 * TD + t] * S;
    // bin = floor(x·v * S + 32), clipped to [0,63]

    // batch of first point: largest b with offs[b] <= start (uniform)
    int lo = 0, hi = NB;
    while (lo < hi) {
        int mid = (lo + hi + 1) >> 1;
        if (offs[mid] <= start) lo = mid; else hi = mid - 1;
    }
    int b = lo;

    // point j's coord k at flat tile offset q=3j+k -> register q>>6, lane q&63
    // (compile-time constants after full unroll -> v_readlane broadcast).
#define SELREG(q, r0, r1, r2) ((q) < 64 ? (r0) : ((q) < 128 ? (r1) : (r2)))
#define RD(q, r0, r1, r2) __uint_as_float(__builtin_amdgcn_readlane(           \
        __float_as_uint(SELREG(q, r0, r1, r2)), (q) & 63))
#define PROC1(j, r0, r1, r2) {                                                 \
        float x0 = RD(3*(j), r0,r1,r2), x1 = RD(3*(j)+1, r0,r1,r2),            \
              x2 = RD(3*(j)+2, r0,r1,r2);                                      \
        float f = fmaf(x0, v0S, fmaf(x1, v1S, fmaf(x2, v2S, 32.0f)));          \
        f = __builtin_amdgcn_fmed3f(f, 0.0f, 63.0f);                           \
        int bin = (int)f;                                                      \
        atomicAdd(&hw[(bin << 6) + t], 1u); }

    int seg = start;
    while (seg < stop) {                          // one iter per batch segment
        while (offs[b + 1] <= seg) ++b;           // skip empty batches (uniform)
        const int segend = min(stop, offs[b + 1]);

        for (int i = threadIdx.x; i < 2 * RES * TD; i += BLK) hist[0][i] = 0u;
        __syncthreads();

        const int npts = segend - seg;
        const int nf = npts >> 6;                 // full 64-point tiles

        // software-pipelined full tiles: issue next tile's loads, then
        // process current tile from registers (~1300 cyc covers VMEM latency)
        float c0, c1, c2, n0, n1, n2;
        int tl = w;
        if (tl < nf) {
            const int fb = 3 * (seg + (tl << 6)) + t;
            c0 = x[fb]; c1 = x[fb + 64]; c2 = x[fb + 128];
        }
        for (; tl < nf; tl += WAVES) {
            const int tn = tl + WAVES;
            if (tn < nf) {                        // prefetch next tile (uniform)
                const int fb = 3 * (seg + (tn << 6)) + t;
                n0 = x[fb]; n1 = x[fb + 64]; n2 = x[fb + 128];
            }
            #pragma unroll
            for (int j = 0; j < 64; ++j) PROC1(j, c0, c1, c2);
            if (tn < nf) { c0 = n0; c1 = n1; c2 = n2; }
        }

        // ragged segment-tail tile (at most one), owned by wave (nf mod 16)
        const int rem = npts & 63;
        if (rem && w == (nf & (WAVES - 1))) {
            const int fb = 3 * (seg + (nf << 6)) + t;
            const int lim = 3 * segend;
            float l0 = (fb       < lim) ? x[fb]       : 0.0f;
            float l1 = (fb +  64 < lim) ? x[fb +  64] : 0.0f;
            float l2 = (fb + 128 < lim) ? x[fb + 128] : 0.0f;
            #pragma unroll
            for (int j = 0; j < 64; ++j) {
                if (j < rem) PROC1(j, l0, l1, l2);   // wave-uniform guard
            }
        }
        __syncthreads();

        // flush both block-private histograms into batch b's slab (exact uint)
        unsigned* __restrict__ gb = counts + b * (RES * TD);
        for (int i = threadIdx.x; i < RES * TD; i += BLK) {
            unsigned h = hist[0][i] + hist[1][i];
            if (h) atomicAdd(&gb[i], h);
        }
        if (segend < stop) __syncthreads();       // before re-zeroing hist
        seg = segend;
    }
#undef PROC1
#undef RD
#undef SELREG
}

// In-place: d_out holds uint counts [64][64][64]; convert to cumulative f32
// over the bin axis. One block per batch b, lane t owns column (b,t).
__global__ __launch_bounds__(64) void ect_cumsum_kernel(unsigned* __restrict__ u)
{
    int b = blockIdx.x, t = threadIdx.x;
    int base = b * (RES * TD) + t;

    unsigned vals[RES];
    #pragma unroll
    for (int r = 0; r < RES; ++r) vals[r] = u[base + (r << 6)];

    unsigned acc = 0u;
    #pragma unroll
    for (int r = 0; r < RES; ++r) {
        acc += vals[r];
        u[base + (r << 6)] = __float_as_uint((float)acc);  // counts < 2^24: exact
    }
}

extern "C" void kernel_launch(void* const* d_in, const int* in_sizes, int n_in,
                              void* d_out, int out_size, void* d_ws, size_t ws_size,
                              hipStream_t stream) {
    const float* x = (const float*)d_in[0];          // [N,3]
    const float* v = (const float*)d_in[1];          // [3,64]
    const int* batch = (const int*)d_in[2];          // [N] int32, sorted
    const int N = in_sizes[2];
    int* offs = (int*)d_ws;                          // 65 ints of scratch

    ect_init_kernel<<<(NB * RES * TD) / 256, 256, 0, stream>>>(
        batch, N, (unsigned*)d_out, offs);

    const int nblocks = (N + CHUNK - 1) / CHUNK;     // 512 for N=1M
    ect_hist_kernel<<<nblocks, BLK, 0, stream>>>(x, v, offs, (unsigned*)d_out, N);

    ect_cumsum_kernel<<<NB, 64, 0, stream>>>((unsigned*)d_out);
}